// Round 1
// baseline (1082.089 us; speedup 1.0000x reference)
//
#include <hip/hip_runtime.h>
#include <hip/hip_bf16.h>

// ---------------------------------------------------------------------------
// SelfAttention: QKV = X@W ; S = Q K^T / sqrt(512) ; P = softmax(S, axis=q) ;
// out = P @ V.   B=4, S=4096, D_IN=1024, A=512, O=1024.
// Softmax is over the *q* axis (per key column) -> two-pass: column sums, then
// out[q,o] = sum_k exp(S[q,k]) * (V[k,o] / l[k]).  exp never overflows (S~N(0,1)).
// ---------------------------------------------------------------------------

typedef unsigned int u32;
typedef unsigned short u16;
typedef __bf16 bf16x8 __attribute__((ext_vector_type(8)));
typedef float f32x4 __attribute__((ext_vector_type(4)));
typedef u16 ushort4_t __attribute__((ext_vector_type(4)));
typedef u16 ushort8_t __attribute__((ext_vector_type(8)));

#define SCL 0.04419417382415922f   // 1/sqrt(512)

// async global->LDS, 16B per lane, wave-uniform LDS base
#define GLOAD16(gp, lp)                                                        \
  __builtin_amdgcn_global_load_lds(                                            \
      (const __attribute__((address_space(1))) u32*)(gp),                      \
      (__attribute__((address_space(3))) u32*)(lp), 16, 0, 0)

__device__ __forceinline__ u16 f2bf(float f) {
  union { float f; u32 u; } v; v.f = f;
  u32 r = (v.u + 0x7fffu + ((v.u >> 16) & 1u)) >> 16;   // RNE
  return (u16)r;
}
__device__ __forceinline__ float bf2f(u16 h) {
  union { u32 u; float f; } v; v.u = ((u32)h) << 16;
  return v.f;
}

// ---------------- K1: X fp32 -> bf16 -------------------------------------
__global__ __launch_bounds__(256) void k_cvt_x(const float* __restrict__ X,
                                               u16* __restrict__ Xb) {
  size_t i = ((size_t)blockIdx.x * 256 + threadIdx.x) * 8;
  const float4* p = (const float4*)(X + i);
  float4 a = p[0], b = p[1];
  ushort8_t o;
  o[0] = f2bf(a.x); o[1] = f2bf(a.y); o[2] = f2bf(a.z); o[3] = f2bf(a.w);
  o[4] = f2bf(b.x); o[5] = f2bf(b.y); o[6] = f2bf(b.z); o[7] = f2bf(b.w);
  *(ushort8_t*)(Xb + i) = o;
}

// ---------------- K2: W [1024][2048] fp32 -> Wbt [2048][1024] bf16 --------
__global__ __launch_bounds__(256) void k_cvt_w(const float* __restrict__ W,
                                               u16* __restrict__ Wbt) {
  __shared__ float t[64][65];
  const int e0 = blockIdx.x * 64, d0 = blockIdx.y * 64;
  const int c = threadIdx.x & 63, r4 = threadIdx.x >> 6;
#pragma unroll
  for (int i = 0; i < 16; i++) {
    int d = r4 + i * 4;
    t[d][c] = W[(size_t)(d0 + d) * 2048 + e0 + c];
  }
  __syncthreads();
#pragma unroll
  for (int i = 0; i < 16; i++) {
    int e = r4 + i * 4;
    Wbt[(size_t)(e0 + e) * 1024 + d0 + c] = f2bf(t[c][e]);
  }
}

// ---------------- K3: QKV GEMM (m97-style 128x128, BK=32) ------------------
// C[r][e] = sum_d Xb[r][d]*Wbt[e][d].  e<512 -> Qb ; e<1024 -> Kb ; else Vt^T.
__global__ __launch_bounds__(256) void k_qkv(const u16* __restrict__ Xb,
                                             const u16* __restrict__ Wbt,
                                             u16* __restrict__ Qb,
                                             u16* __restrict__ Kb,
                                             u16* __restrict__ Vt) {
  __shared__ u16 As[128 * 32];
  __shared__ u16 Bs[128 * 32];
  const int tid = threadIdx.x;
  const int w = tid >> 6, l = tid & 63;
  const int r0 = blockIdx.y * 128, c0 = blockIdx.x * 128;
  const int wr = w >> 1, wc = w & 1;
  const int lr = l & 15, lg = l >> 4;
  f32x4 acc[4][4] = {};
  for (int k0 = 0; k0 < 1024; k0 += 32) {
    __syncthreads();
#pragma unroll
    for (int i = 0; i < 2; i++) {
      int j = w + 4 * i;                 // wave-load index 0..7
      int ro = j * 16 + (l >> 2);
      int co = (l & 3) * 8;
      GLOAD16(Xb + (size_t)(r0 + ro) * 1024 + k0 + co, &As[j * 512]);
      GLOAD16(Wbt + (size_t)(c0 + ro) * 1024 + k0 + co, &Bs[j * 512]);
    }
    __syncthreads();
    bf16x8 a[4], b[4];
#pragma unroll
    for (int m = 0; m < 4; m++)
      a[m] = *(const bf16x8*)&As[(wr * 64 + m * 16 + lr) * 32 + lg * 8];
#pragma unroll
    for (int n = 0; n < 4; n++)
      b[n] = *(const bf16x8*)&Bs[(wc * 64 + n * 16 + lr) * 32 + lg * 8];
#pragma unroll
    for (int m = 0; m < 4; m++)
#pragma unroll
      for (int n = 0; n < 4; n++)
        acc[m][n] = __builtin_amdgcn_mfma_f32_16x16x32_bf16(a[m], b[n], acc[m][n], 0, 0, 0);
  }
  const int bb = r0 >> 12;
  const int s0 = (r0 & 4095) + wr * 64;
#pragma unroll
  for (int m = 0; m < 4; m++) {
    int sb = s0 + m * 16 + lg * 4;
#pragma unroll
    for (int n = 0; n < 4; n++) {
      int e16 = c0 + wc * 64 + n * 16;   // wave-uniform region select
      f32x4 v = acc[m][n];
      if (e16 < 1024) {
        u16* base; int ee;
        if (e16 < 512) { base = Qb; ee = e16 + lr; }
        else           { base = Kb; ee = e16 - 512 + lr; }
#pragma unroll
        for (int j = 0; j < 4; j++)
          base[((size_t)bb * 4096 + sb + j) * 512 + ee] = f2bf(v[j]);
      } else {
        int o = e16 - 1024 + lr;
        ushort4_t pk = { f2bf(v[0]), f2bf(v[1]), f2bf(v[2]), f2bf(v[3]) };
        *(ushort4_t*)(Vt + ((size_t)bb * 1024 + o) * 4096 + sb) = pk;
      }
    }
  }
}

// ---------------- K4: column sums  linv[b][k] = 1/sum_q exp(S) -------------
// Block: 64-key strip, all 4096 q.  K strip LDS-resident (chunk-XOR swizzle),
// Q double-buffered in registers.
__global__ __launch_bounds__(256) void k_stats(const u16* __restrict__ Qb,
                                               const u16* __restrict__ Kb,
                                               float* __restrict__ linv) {
  __shared__ u16 Ks[64 * 512];           // 64 rows x 1KB, swizzled 16B chunks
  __shared__ float red[4][4][16];
  const int tid = threadIdx.x;
  const int w = tid >> 6, l = tid & 63;
  const int lr = l & 15, lg = l >> 4;
  const int b = blockIdx.y;
  const int k0 = blockIdx.x * 64;
#pragma unroll
  for (int i = 0; i < 16; i++) {
    int r = w * 16 + i;
    int c = l ^ (r & 7);                 // pre-swizzled global source chunk
    GLOAD16(Kb + ((size_t)b * 4096 + k0 + r) * 512 + c * 8, &Ks[r * 512]);
  }
  __syncthreads();
  float lsum[4] = {0.f, 0.f, 0.f, 0.f};
  bf16x8 qa[16], qb[16];
  const u16* qbase = Qb + ((size_t)b * 4096 + w * 16 + lr) * 512 + lg * 8;
  auto loadQ = [&](int qc, bf16x8* qf) {
    const u16* p = qbase + (size_t)qc * 64 * 512;
#pragma unroll
    for (int s = 0; s < 16; s++) qf[s] = *(const bf16x8*)(p + s * 32);
  };
  auto proc = [&](bf16x8* qf) {
    f32x4 sacc[4] = {};
#pragma unroll
    for (int s = 0; s < 16; s++) {
#pragma unroll
      for (int n = 0; n < 4; n++) {
        int r = n * 16 + lr;
        int c = s * 4 + lg;
        bf16x8 kb = *(const bf16x8*)&Ks[r * 512 + (c ^ (r & 7)) * 8];
        sacc[n] = __builtin_amdgcn_mfma_f32_16x16x32_bf16(qf[s], kb, sacc[n], 0, 0, 0);
      }
    }
#pragma unroll
    for (int n = 0; n < 4; n++) {
      float v = __expf(sacc[n][0] * SCL) + __expf(sacc[n][1] * SCL) +
                __expf(sacc[n][2] * SCL) + __expf(sacc[n][3] * SCL);
      v += __shfl_xor(v, 16);
      v += __shfl_xor(v, 32);            // all lanes: 16-row sum for col lr
      lsum[n] += v;
    }
  };
  loadQ(0, qa);
  for (int qc = 0; qc < 64; qc += 2) {
    loadQ(qc + 1, qb);
    proc(qa);
    loadQ((qc + 2) & 63, qa);
    proc(qb);
  }
#pragma unroll
  for (int n = 0; n < 4; n++)
    if (l < 16) red[w][n][lr] = lsum[n];
  __syncthreads();
  if (tid < 64) {
    float t = red[0][tid >> 4][tid & 15] + red[1][tid >> 4][tid & 15] +
              red[2][tid >> 4][tid & 15] + red[3][tid >> 4][tid & 15];
    linv[(size_t)b * 4096 + k0 + tid] = 1.0f / t;
  }
}

// ---------------- K5: Vt[b][o][k] *= linv[b][k] ---------------------------
__global__ __launch_bounds__(256) void k_scale(u16* __restrict__ Vt,
                                               const float* __restrict__ linv) {
  size_t i = ((size_t)blockIdx.x * 256 + threadIdx.x) * 8;
  int b = (int)(i >> 22);
  int k = (int)(i & 4095);
  const float* lp = linv + ((size_t)b << 12) + k;
  ushort8_t v = *(ushort8_t*)(Vt + i);
#pragma unroll
  for (int j = 0; j < 8; j++) v[j] = f2bf(bf2f(v[j]) * lp[j]);
  *(ushort8_t*)(Vt + i) = v;
}

// ---------------- K6: out = exp(QK^T/s) @ Vt' -----------------------------
// Block: 128 q x 512 o, 8 waves (2x4).  Per 64-key step: stage K/Vt (swizzled),
// S via MFMA -> exp -> P in LDS -> PV MFMA.
__global__ __launch_bounds__(512) void k_attn(const u16* __restrict__ Qb,
                                              const u16* __restrict__ Kb,
                                              const u16* __restrict__ Vt,
                                              float* __restrict__ out) {
  __shared__ u16 Ks[64 * 512];           // 64KB
  __shared__ u16 Vs[512 * 64];           // 64KB
  __shared__ u16 Ps[128 * 64];           // 16KB
  const int tid = threadIdx.x;
  const int w = tid >> 6, l = tid & 63;
  const int lr = l & 15, lg = l >> 4;
  const int b = blockIdx.z;
  const int q0 = blockIdx.x * 128;
  const int o0 = blockIdx.y * 512;
  const int wr = w >> 2, wc = w & 3;
  bf16x8 qf[16];                         // wave's 16 phase-1 q rows, K=512
  {
    const u16* p = Qb + ((size_t)b * 4096 + q0 + w * 16 + lr) * 512 + lg * 8;
#pragma unroll
    for (int s = 0; s < 16; s++) qf[s] = *(const bf16x8*)(p + s * 32);
  }
  f32x4 acc[4][8] = {};
  for (int k0 = 0; k0 < 4096; k0 += 64) {
    __syncthreads();
#pragma unroll
    for (int i = 0; i < 8; i++) {        // K tile: 64 rows x 1KB
      int r = w * 8 + i;
      int c = l ^ (r & 7);
      GLOAD16(Kb + ((size_t)b * 4096 + k0 + r) * 512 + c * 8, &Ks[r * 512]);
    }
#pragma unroll
    for (int i = 0; i < 8; i++) {        // Vt tile: 512 rows x 128B
      int rb = w * 64 + i * 8;
      int r = rb + (l >> 3);
      int c = (l & 7) ^ (r & 7);
      GLOAD16(Vt + ((size_t)b * 1024 + o0 + r) * 4096 + k0 + c * 8, &Vs[rb * 64]);
    }
    __syncthreads();
    // phase 1: S rows w*16..+16 x 64 keys
    f32x4 sacc[4] = {};
#pragma unroll
    for (int s = 0; s < 16; s++) {
#pragma unroll
      for (int n = 0; n < 4; n++) {
        int r = n * 16 + lr;
        int c = s * 4 + lg;
        bf16x8 kb = *(const bf16x8*)&Ks[r * 512 + (c ^ (r & 7)) * 8];
        sacc[n] = __builtin_amdgcn_mfma_f32_16x16x32_bf16(qf[s], kb, sacc[n], 0, 0, 0);
      }
    }
#pragma unroll
    for (int n = 0; n < 4; n++) {
#pragma unroll
      for (int j = 0; j < 4; j++) {
        int q = w * 16 + lg * 4 + j;
        int k = n * 16 + lr;
        int cc = k >> 3;
        Ps[q * 64 + ((cc ^ (q & 7)) * 8) + (k & 7)] = f2bf(__expf(sacc[n][j] * SCL));
      }
    }
    __syncthreads();
    // phase 2: out(64q x 128o) += P(64x64) @ Vt'(64x128)
    bf16x8 pf[4][2];
#pragma unroll
    for (int m = 0; m < 4; m++)
#pragma unroll
      for (int s = 0; s < 2; s++) {
        int q = wr * 64 + m * 16 + lr;
        int c = s * 4 + lg;
        pf[m][s] = *(const bf16x8*)&Ps[q * 64 + ((c ^ (q & 7)) * 8)];
      }
#pragma unroll
    for (int t = 0; t < 8; t++) {
#pragma unroll
      for (int s = 0; s < 2; s++) {
        int o = wc * 128 + t * 16 + lr;
        int c = s * 4 + lg;
        bf16x8 vb = *(const bf16x8*)&Vs[o * 64 + ((c ^ (o & 7)) * 8)];
#pragma unroll
        for (int m = 0; m < 4; m++)
          acc[m][t] = __builtin_amdgcn_mfma_f32_16x16x32_bf16(pf[m][s], vb, acc[m][t], 0, 0, 0);
      }
    }
  }
#pragma unroll
  for (int m = 0; m < 4; m++) {
    int q = q0 + wr * 64 + m * 16 + lg * 4;
#pragma unroll
    for (int t = 0; t < 8; t++) {
      int o = o0 + wc * 128 + t * 16 + lr;
#pragma unroll
      for (int j = 0; j < 4; j++)
        out[((size_t)b * 4096 + q + j) * 1024 + o] = acc[m][t][j];
    }
  }
}

// ---------------------------------------------------------------------------
extern "C" void kernel_launch(void* const* d_in, const int* in_sizes, int n_in,
                              void* d_out, int out_size, void* d_ws, size_t ws_size,
                              hipStream_t stream) {
  const float* X = (const float*)d_in[0];   // 4*4096*1024
  const float* W = (const float*)d_in[1];   // 1024*2048
  float* out = (float*)d_out;               // 4*4096*1024 fp32
  char* ws = (char*)d_ws;
  // workspace layout (bytes): needs ~100.1 MB
  u16* Xb   = (u16*)(ws);                   // 33554432
  u16* Wbt  = (u16*)(ws + 33554432);        //  4194304
  u16* Qb   = (u16*)(ws + 37748736);        // 16777216
  u16* Kb   = (u16*)(ws + 54525952);        // 16777216
  u16* Vt   = (u16*)(ws + 71303168);        // 33554432
  float* linv = (float*)(ws + 104857600);   //    65536
  if (ws_size < 104923136) return;          // workspace requirement

  k_cvt_x<<<dim3(8192), dim3(256), 0, stream>>>(X, Xb);
  k_cvt_w<<<dim3(32, 16), dim3(256), 0, stream>>>(W, Wbt);
  k_qkv<<<dim3(16, 128), dim3(256), 0, stream>>>(Xb, Wbt, Qb, Kb, Vt);
  k_stats<<<dim3(64, 4), dim3(256), 0, stream>>>(Qb, Kb, linv);
  k_scale<<<dim3(8192), dim3(256), 0, stream>>>(Vt, linv);
  k_attn<<<dim3(32, 2, 4), dim3(512), 0, stream>>>(Qb, Kb, Vt, out);
}

// Round 2
// 442.216 us; speedup vs baseline: 2.4470x; 2.4470x over previous
//
#include <hip/hip_runtime.h>
#include <hip/hip_bf16.h>

// ---------------------------------------------------------------------------
// SelfAttention: QKV = X@W ; S = Q K^T / sqrt(512) ; P = softmax(S, axis=q) ;
// out = P @ V.   B=4, S=4096, D_IN=1024, A=512, O=1024.
// Softmax over the *q* axis (per key column).  Strategy: materialize
// P = exp(S) (unnormalized, bf16) with a GEMM+epilogue kernel that also emits
// per-block column partial sums; fold 1/l into Vt; finish with a pure GEMM
// out = P @ Vt'.  exp never overflows (S ~ N(0,1)).
// ---------------------------------------------------------------------------

typedef unsigned int u32;
typedef unsigned short u16;
typedef __bf16 bf16x8 __attribute__((ext_vector_type(8)));
typedef float f32x4 __attribute__((ext_vector_type(4)));
typedef u16 ushort8_t __attribute__((ext_vector_type(8)));

#define SCL 0.04419417382415922f   // 1/sqrt(512)

// async global->LDS, 16B per lane, wave-uniform LDS base
#define GLOAD16(gp, lp)                                                        \
  __builtin_amdgcn_global_load_lds(                                            \
      (const __attribute__((address_space(1))) u32*)(gp),                      \
      (__attribute__((address_space(3))) u32*)(lp), 16, 0, 0)

__device__ __forceinline__ u16 f2bf(float f) {
  union { float f; u32 u; } v; v.f = f;
  u32 r = (v.u + 0x7fffu + ((v.u >> 16) & 1u)) >> 16;   // RNE
  return (u16)r;
}
__device__ __forceinline__ float bf2f(u16 h) {
  union { u32 u; float f; } v; v.u = ((u32)h) << 16;
  return v.f;
}

// ---------------- K1: X fp32 -> bf16 -------------------------------------
__global__ __launch_bounds__(256) void k_cvt_x(const float* __restrict__ X,
                                               u16* __restrict__ Xb) {
  size_t i = ((size_t)blockIdx.x * 256 + threadIdx.x) * 8;
  const float4* p = (const float4*)(X + i);
  float4 a = p[0], b = p[1];
  ushort8_t o;
  o[0] = f2bf(a.x); o[1] = f2bf(a.y); o[2] = f2bf(a.z); o[3] = f2bf(a.w);
  o[4] = f2bf(b.x); o[5] = f2bf(b.y); o[6] = f2bf(b.z); o[7] = f2bf(b.w);
  *(ushort8_t*)(Xb + i) = o;
}

// ---------------- K2: W [1024][2048] fp32 -> Wbt [2048][1024] bf16 --------
__global__ __launch_bounds__(256) void k_cvt_w(const float* __restrict__ W,
                                               u16* __restrict__ Wbt) {
  __shared__ float t[64][65];
  const int e0 = blockIdx.x * 64, d0 = blockIdx.y * 64;
  const int c = threadIdx.x & 63, r4 = threadIdx.x >> 6;
#pragma unroll
  for (int i = 0; i < 16; i++) {
    int d = r4 + i * 4;
    t[d][c] = W[(size_t)(d0 + d) * 2048 + e0 + c];
  }
  __syncthreads();
#pragma unroll
  for (int i = 0; i < 16; i++) {
    int e = r4 + i * 4;
    Wbt[(size_t)(e0 + e) * 1024 + d0 + c] = f2bf(t[c][e]);
  }
}

// ---------------- K3: QKV GEMM (m97-style 128x128, BK=32) ------------------
// C[r][e] = sum_d Xb[r][d]*Wbt[e][d].  e<512 -> Qb ; e<1024 -> Kb ; else Vt^T.
__global__ __launch_bounds__(256) void k_qkv(const u16* __restrict__ Xb,
                                             const u16* __restrict__ Wbt,
                                             u16* __restrict__ Qb,
                                             u16* __restrict__ Kb,
                                             u16* __restrict__ Vt) {
  __shared__ u16 As[128 * 32];
  __shared__ u16 Bs[128 * 32];
  const int tid = threadIdx.x;
  const int w = tid >> 6, l = tid & 63;
  const int r0 = blockIdx.y * 128, c0 = blockIdx.x * 128;
  const int wr = w >> 1, wc = w & 1;
  const int lr = l & 15, lg = l >> 4;
  f32x4 acc[4][4] = {};
  for (int k0 = 0; k0 < 1024; k0 += 32) {
    __syncthreads();
#pragma unroll
    for (int i = 0; i < 2; i++) {
      int j = w + 4 * i;                 // wave-load index 0..7
      int ro = j * 16 + (l >> 2);
      int co = (l & 3) * 8;
      GLOAD16(Xb + (size_t)(r0 + ro) * 1024 + k0 + co, &As[j * 512]);
      GLOAD16(Wbt + (size_t)(c0 + ro) * 1024 + k0 + co, &Bs[j * 512]);
    }
    __syncthreads();
    bf16x8 a[4], b[4];
#pragma unroll
    for (int m = 0; m < 4; m++)
      a[m] = *(const bf16x8*)&As[(wr * 64 + m * 16 + lr) * 32 + lg * 8];
#pragma unroll
    for (int n = 0; n < 4; n++)
      b[n] = *(const bf16x8*)&Bs[(wc * 64 + n * 16 + lr) * 32 + lg * 8];
#pragma unroll
    for (int m = 0; m < 4; m++)
#pragma unroll
      for (int n = 0; n < 4; n++)
        acc[m][n] = __builtin_amdgcn_mfma_f32_16x16x32_bf16(a[m], b[n], acc[m][n], 0, 0, 0);
  }
  const int bb = r0 >> 12;
  const int s0 = (r0 & 4095) + wr * 64;
#pragma unroll
  for (int m = 0; m < 4; m++) {
    int sb = s0 + m * 16 + lg * 4;
#pragma unroll
    for (int n = 0; n < 4; n++) {
      int e16 = c0 + wc * 64 + n * 16;   // wave-uniform region select
      f32x4 v = acc[m][n];
      if (e16 < 1024) {
        u16* base; int ee;
        if (e16 < 512) { base = Qb; ee = e16 + lr; }
        else           { base = Kb; ee = e16 - 512 + lr; }
#pragma unroll
        for (int j = 0; j < 4; j++)
          base[((size_t)bb * 4096 + sb + j) * 512 + ee] = f2bf(v[j]);
      } else {
        int o = e16 - 1024 + lr;
        u16 pk[4] = { f2bf(v[0]), f2bf(v[1]), f2bf(v[2]), f2bf(v[3]) };
        *(uint2*)(Vt + ((size_t)bb * 1024 + o) * 4096 + sb) = *(uint2*)pk;
      }
    }
  }
}

// ---------------- K4: S-GEMM + exp -> P, column partial sums ---------------
// Per block: 128 q x 128 k tile.  P[bl][q][k] = exp(QK^T*SCL) bf16;
// part[bl][qb][k] = sum over the block's 128 q rows.
__global__ __launch_bounds__(256) void k_sp(const u16* __restrict__ Qb,
                                            const u16* __restrict__ Kb,
                                            u16* __restrict__ P,
                                            float* __restrict__ part,
                                            int b0) {
  __shared__ u16 As[128 * 32];
  __shared__ u16 Bs[128 * 32];
  __shared__ u16 Pst[128 * 136];
  __shared__ float red[2][2][4][16];
  const int tid = threadIdx.x;
  const int w = tid >> 6, l = tid & 63;
  const int wr = w >> 1, wc = w & 1;
  const int lr = l & 15, lg = l >> 4;
  const int q0 = blockIdx.y * 128, kk0 = blockIdx.x * 128;
  const int bl = blockIdx.z, b = b0 + bl;
  const u16* Ab = Qb + ((size_t)b * 4096 + q0) * 512;
  const u16* Bb = Kb + ((size_t)b * 4096 + kk0) * 512;
  f32x4 acc[4][4] = {};
  for (int a0 = 0; a0 < 512; a0 += 32) {
    __syncthreads();
#pragma unroll
    for (int i = 0; i < 2; i++) {
      int j = w + 4 * i;
      int ro = j * 16 + (l >> 2);
      int co = (l & 3) * 8;
      GLOAD16(Ab + (size_t)ro * 512 + a0 + co, &As[j * 512]);
      GLOAD16(Bb + (size_t)ro * 512 + a0 + co, &Bs[j * 512]);
    }
    __syncthreads();
    bf16x8 a[4], bfr[4];
#pragma unroll
    for (int m = 0; m < 4; m++)
      a[m] = *(const bf16x8*)&As[(wr * 64 + m * 16 + lr) * 32 + lg * 8];
#pragma unroll
    for (int n = 0; n < 4; n++)
      bfr[n] = *(const bf16x8*)&Bs[(wc * 64 + n * 16 + lr) * 32 + lg * 8];
#pragma unroll
    for (int m = 0; m < 4; m++)
#pragma unroll
      for (int n = 0; n < 4; n++)
        acc[m][n] = __builtin_amdgcn_mfma_f32_16x16x32_bf16(a[m], bfr[n], acc[m][n], 0, 0, 0);
  }
  // epilogue: exp, stage P tile in LDS (pad 136 avoids 4-way conflicts),
  // accumulate column sums
  float cs[4] = {0.f, 0.f, 0.f, 0.f};
#pragma unroll
  for (int m = 0; m < 4; m++) {
#pragma unroll
    for (int n = 0; n < 4; n++) {
      f32x4 v = acc[m][n];
#pragma unroll
      for (int j = 0; j < 4; j++) {
        float p = __expf(v[j] * SCL);
        cs[n] += p;
        Pst[(wr * 64 + m * 16 + lg * 4 + j) * 136 + wc * 64 + n * 16 + lr] = f2bf(p);
      }
    }
  }
#pragma unroll
  for (int n = 0; n < 4; n++) {
    cs[n] += __shfl_xor(cs[n], 16);
    cs[n] += __shfl_xor(cs[n], 32);
    if (l < 16) red[wr][wc][n][lr] = cs[n];
  }
  __syncthreads();
  if (tid < 128) {
    int wcb = tid >> 6, nn = (tid >> 4) & 3, lrr = tid & 15;
    float v = red[0][wcb][nn][lrr] + red[1][wcb][nn][lrr];
    part[((size_t)(bl * 32 + blockIdx.y)) * 4096 + kk0 + tid] = v;
  }
  // coalesced P write: 8 lanes x 16B = 128B row segments
#pragma unroll
  for (int i = 0; i < 4; i++) {
    int r = i * 32 + (tid >> 3);
#pragma unroll
    for (int j2 = 0; j2 < 2; j2++) {
      int col = (tid & 7) * 8 + j2 * 64;
      *(ushort8_t*)&P[((size_t)bl * 4096 + q0 + r) * 4096 + kk0 + col] =
          *(const ushort8_t*)&Pst[r * 136 + col];
    }
  }
}

// ---------------- K5: linv[bl][k] = 1 / sum_qb part[bl][qb][k] -------------
__global__ __launch_bounds__(256) void k_finl(const float* __restrict__ part,
                                              float* __restrict__ linv) {
  int t = blockIdx.x * 256 + threadIdx.x;   // t < G*4096
  int bl = t >> 12, k = t & 4095;
  float s = 0.f;
#pragma unroll
  for (int qb = 0; qb < 32; qb++)
    s += part[((size_t)(bl * 32 + qb)) * 4096 + k];
  linv[t] = 1.0f / s;
}

// ---------------- K6: Vt[bl][o][k] *= linv[bl][k] -------------------------
__global__ __launch_bounds__(256) void k_scale(u16* __restrict__ Vtg,
                                               const float* __restrict__ linv) {
  size_t i = ((size_t)blockIdx.x * 256 + threadIdx.x) * 8;
  int bl = (int)(i >> 22);
  int k = (int)(i & 4095);
  const float* lp = linv + ((size_t)bl << 12) + k;
  ushort8_t v = *(ushort8_t*)(Vtg + i);
#pragma unroll
  for (int j = 0; j < 8; j++) v[j] = f2bf(bf2f(v[j]) * lp[j]);
  *(ushort8_t*)(Vtg + i) = v;
}

// ---------------- K7: out = P @ Vt'  (pure GEMM, K=4096) ------------------
__global__ __launch_bounds__(256) void k_pv(const u16* __restrict__ P,
                                            const u16* __restrict__ Vtg,
                                            float* __restrict__ outg) {
  __shared__ u16 As[128 * 32];
  __shared__ u16 Bs[128 * 32];
  const int tid = threadIdx.x;
  const int w = tid >> 6, l = tid & 63;
  const int wr = w >> 1, wc = w & 1;
  const int lr = l & 15, lg = l >> 4;
  const int q0 = blockIdx.y * 128, o0 = blockIdx.x * 128;
  const int bl = blockIdx.z;
  const u16* Ab = P + ((size_t)bl * 4096 + q0) * 4096;
  const u16* Bb = Vtg + ((size_t)bl * 1024 + o0) * 4096;
  f32x4 acc[4][4] = {};
  for (int a0 = 0; a0 < 4096; a0 += 32) {
    __syncthreads();
#pragma unroll
    for (int i = 0; i < 2; i++) {
      int j = w + 4 * i;
      int ro = j * 16 + (l >> 2);
      int co = (l & 3) * 8;
      GLOAD16(Ab + (size_t)ro * 4096 + a0 + co, &As[j * 512]);
      GLOAD16(Bb + (size_t)ro * 4096 + a0 + co, &Bs[j * 512]);
    }
    __syncthreads();
    bf16x8 a[4], bfr[4];
#pragma unroll
    for (int m = 0; m < 4; m++)
      a[m] = *(const bf16x8*)&As[(wr * 64 + m * 16 + lr) * 32 + lg * 8];
#pragma unroll
    for (int n = 0; n < 4; n++)
      bfr[n] = *(const bf16x8*)&Bs[(wc * 64 + n * 16 + lr) * 32 + lg * 8];
#pragma unroll
    for (int m = 0; m < 4; m++)
#pragma unroll
      for (int n = 0; n < 4; n++)
        acc[m][n] = __builtin_amdgcn_mfma_f32_16x16x32_bf16(a[m], bfr[n], acc[m][n], 0, 0, 0);
  }
#pragma unroll
  for (int m = 0; m < 4; m++) {
    int q = q0 + wr * 64 + m * 16 + lg * 4;
#pragma unroll
    for (int n = 0; n < 4; n++) {
      int o = o0 + wc * 64 + n * 16 + lr;
      f32x4 v = acc[m][n];
#pragma unroll
      for (int j = 0; j < 4; j++)
        outg[((size_t)bl * 4096 + q + j) * 1024 + o] = v[j];
    }
  }
}

// ---------------------------------------------------------------------------
extern "C" void kernel_launch(void* const* d_in, const int* in_sizes, int n_in,
                              void* d_out, int out_size, void* d_ws, size_t ws_size,
                              hipStream_t stream) {
  const float* X = (const float*)d_in[0];   // 4*4096*1024
  const float* W = (const float*)d_in[1];   // 1024*2048
  float* out = (float*)d_out;               // 4*4096*1024 fp32
  char* ws = (char*)d_ws;

  // batch-group size G by available workspace
  int G;
  if (ws_size >= 203489280ull)      G = 4;   // P = 128MB, single pass
  else if (ws_size >= 135299072ull) G = 2;   // P = 64MB, two passes
  else if (ws_size >= 104857600ull) G = 1;   // P = 32MB, four passes
  else return;
  const size_t PB = (size_t)G * 33554432ull;

  // layout (bytes):
  //   Qb @ 0          (16MB)   bf16 [4][4096][512]
  //   Kb @ 16MB       (16MB)   bf16 [4][4096][512]
  //   Vt @ 32MB       (32MB)   bf16 [4][1024][4096]  (V transposed)
  //   P  @ 64MB       (PB)     bf16 [G][4096][4096]  exp(S), per group
  //   Xb @ 64MB       (32MB)   aliases P   (dead after k_qkv)
  //   Wbt@ 96MB       (4MB)    aliases P (G>=2) or part-region (G==1)
  //   part @ 64MB+PB  (G*512KB) f32 [G][32][4096]
  //   linv @ +part    (G*16KB)  f32 [G][4096]
  u16* Qb  = (u16*)(ws);
  u16* Kb  = (u16*)(ws + 16777216);
  u16* Vt  = (u16*)(ws + 33554432);
  u16* P   = (u16*)(ws + 67108864);
  u16* Xb  = (u16*)(ws + 67108864);
  u16* Wbt = (u16*)(ws + 100663296);
  float* part = (float*)(ws + 67108864 + PB);
  float* linv = (float*)(ws + 67108864 + PB + (size_t)G * 524288ull);

  k_cvt_x<<<dim3(8192), dim3(256), 0, stream>>>(X, Xb);
  k_cvt_w<<<dim3(32, 16), dim3(256), 0, stream>>>(W, Wbt);
  k_qkv<<<dim3(16, 128), dim3(256), 0, stream>>>(Xb, Wbt, Qb, Kb, Vt);
  for (int b0 = 0; b0 < 4; b0 += G) {
    k_sp<<<dim3(32, 32, G), dim3(256), 0, stream>>>(Qb, Kb, P, part, b0);
    k_finl<<<dim3(G * 16), dim3(256), 0, stream>>>(part, linv);
    k_scale<<<dim3(G * 2048), dim3(256), 0, stream>>>(Vt + (size_t)b0 * 4194304, linv);
    k_pv<<<dim3(8, 32, G), dim3(256), 0, stream>>>(P, Vt + (size_t)b0 * 4194304,
                                                   out + (size_t)b0 * 4194304);
  }
}

// Round 3
// 357.535 us; speedup vs baseline: 3.0265x; 1.2368x over previous
//
#include <hip/hip_runtime.h>
#include <hip/hip_bf16.h>

// ---------------------------------------------------------------------------
// SelfAttention: QKV = X@W ; S = Q K^T / sqrt(512) ; P = softmax(S, axis=q) ;
// out = P @ V.   B=4, S=4096, D_IN=1024, A=512, O=1024.
// Softmax over the *q* axis (per key column).  Strategy: materialize
// P = exp(S) (unnormalized, bf16) with a GEMM+epilogue kernel that also emits
// per-block column partial sums; fold 1/l into Vt; finish with a pure GEMM
// out = P @ Vt'.  exp never overflows (S ~ N(0,1)).
// ---------------------------------------------------------------------------

typedef unsigned int u32;
typedef unsigned short u16;
typedef __bf16 bf16x8 __attribute__((ext_vector_type(8)));
typedef float f32x4 __attribute__((ext_vector_type(4)));
typedef u16 ushort8_t __attribute__((ext_vector_type(8)));

#define SCL 0.04419417382415922f   // 1/sqrt(512)

// async global->LDS, 16B per lane, wave-uniform LDS base
#define GLOAD16(gp, lp)                                                        \
  __builtin_amdgcn_global_load_lds(                                            \
      (const __attribute__((address_space(1))) u32*)(gp),                      \
      (__attribute__((address_space(3))) u32*)(lp), 16, 0, 0)

__device__ __forceinline__ u16 f2bf(float f) {
  union { float f; u32 u; } v; v.f = f;
  u32 r = (v.u + 0x7fffu + ((v.u >> 16) & 1u)) >> 16;   // RNE
  return (u16)r;
}
__device__ __forceinline__ float bf2f(u16 h) {
  union { u32 u; float f; } v; v.u = ((u32)h) << 16;
  return v.f;
}

// ---------------- K1: X fp32 -> bf16 -------------------------------------
__global__ __launch_bounds__(256) void k_cvt_x(const float* __restrict__ X,
                                               u16* __restrict__ Xb) {
  size_t i = ((size_t)blockIdx.x * 256 + threadIdx.x) * 8;
  const float4* p = (const float4*)(X + i);
  float4 a = p[0], b = p[1];
  ushort8_t o;
  o[0] = f2bf(a.x); o[1] = f2bf(a.y); o[2] = f2bf(a.z); o[3] = f2bf(a.w);
  o[4] = f2bf(b.x); o[5] = f2bf(b.y); o[6] = f2bf(b.z); o[7] = f2bf(b.w);
  *(ushort8_t*)(Xb + i) = o;
}

// ---------------- K2: W [1024][2048] fp32 -> Wbt [2048][1024] bf16 --------
__global__ __launch_bounds__(256) void k_cvt_w(const float* __restrict__ W,
                                               u16* __restrict__ Wbt) {
  __shared__ float t[64][65];
  const int e0 = blockIdx.x * 64, d0 = blockIdx.y * 64;
  const int c = threadIdx.x & 63, r4 = threadIdx.x >> 6;
#pragma unroll
  for (int i = 0; i < 16; i++) {
    int d = r4 + i * 4;
    t[d][c] = W[(size_t)(d0 + d) * 2048 + e0 + c];
  }
  __syncthreads();
#pragma unroll
  for (int i = 0; i < 16; i++) {
    int e = r4 + i * 4;
    Wbt[(size_t)(e0 + e) * 1024 + d0 + c] = f2bf(t[c][e]);
  }
}

// ---------------- K3: QKV GEMM (m97-style 128x128, BK=32) ------------------
// C[r][e] = sum_d Xb[r][d]*Wbt[e][d].  e<512 -> Qb ; e<1024 -> Kb ; else Vt^T.
__global__ __launch_bounds__(256) void k_qkv(const u16* __restrict__ Xb,
                                             const u16* __restrict__ Wbt,
                                             u16* __restrict__ Qb,
                                             u16* __restrict__ Kb,
                                             u16* __restrict__ Vt) {
  __shared__ u16 As[128 * 32];
  __shared__ u16 Bs[128 * 32];
  const int tid = threadIdx.x;
  const int w = tid >> 6, l = tid & 63;
  const int r0 = blockIdx.y * 128, c0 = blockIdx.x * 128;
  const int wr = w >> 1, wc = w & 1;
  const int lr = l & 15, lg = l >> 4;
  f32x4 acc[4][4] = {};
  for (int k0 = 0; k0 < 1024; k0 += 32) {
    __syncthreads();
#pragma unroll
    for (int i = 0; i < 2; i++) {
      int j = w + 4 * i;                 // wave-load index 0..7
      int ro = j * 16 + (l >> 2);
      int co = (l & 3) * 8;
      GLOAD16(Xb + (size_t)(r0 + ro) * 1024 + k0 + co, &As[j * 512]);
      GLOAD16(Wbt + (size_t)(c0 + ro) * 1024 + k0 + co, &Bs[j * 512]);
    }
    __syncthreads();
    bf16x8 a[4], b[4];
#pragma unroll
    for (int m = 0; m < 4; m++)
      a[m] = *(const bf16x8*)&As[(wr * 64 + m * 16 + lr) * 32 + lg * 8];
#pragma unroll
    for (int n = 0; n < 4; n++)
      b[n] = *(const bf16x8*)&Bs[(wc * 64 + n * 16 + lr) * 32 + lg * 8];
#pragma unroll
    for (int m = 0; m < 4; m++)
#pragma unroll
      for (int n = 0; n < 4; n++)
        acc[m][n] = __builtin_amdgcn_mfma_f32_16x16x32_bf16(a[m], b[n], acc[m][n], 0, 0, 0);
  }
  const int bb = r0 >> 12;
  const int s0 = (r0 & 4095) + wr * 64;
#pragma unroll
  for (int m = 0; m < 4; m++) {
    int sb = s0 + m * 16 + lg * 4;
#pragma unroll
    for (int n = 0; n < 4; n++) {
      int e16 = c0 + wc * 64 + n * 16;   // wave-uniform region select
      f32x4 v = acc[m][n];
      if (e16 < 1024) {
        u16* base; int ee;
        if (e16 < 512) { base = Qb; ee = e16 + lr; }
        else           { base = Kb; ee = e16 - 512 + lr; }
#pragma unroll
        for (int j = 0; j < 4; j++)
          base[((size_t)bb * 4096 + sb + j) * 512 + ee] = f2bf(v[j]);
      } else {
        int o = e16 - 1024 + lr;
        u16 pk[4] = { f2bf(v[0]), f2bf(v[1]), f2bf(v[2]), f2bf(v[3]) };
        *(uint2*)(Vt + ((size_t)bb * 1024 + o) * 4096 + sb) = *(uint2*)pk;
      }
    }
  }
}

// ---------------- K4: S-GEMM + exp -> P, column partial sums ---------------
__global__ __launch_bounds__(256) void k_sp(const u16* __restrict__ Qb,
                                            const u16* __restrict__ Kb,
                                            u16* __restrict__ P,
                                            float* __restrict__ part,
                                            int b0) {
  __shared__ u16 As[128 * 32];
  __shared__ u16 Bs[128 * 32];
  __shared__ u16 Pst[128 * 136];
  __shared__ float red[2][2][4][16];
  const int tid = threadIdx.x;
  const int w = tid >> 6, l = tid & 63;
  const int wr = w >> 1, wc = w & 1;
  const int lr = l & 15, lg = l >> 4;
  const int q0 = blockIdx.y * 128, kk0 = blockIdx.x * 128;
  const int bl = blockIdx.z, b = b0 + bl;
  const u16* Ab = Qb + ((size_t)b * 4096 + q0) * 512;
  const u16* Bb = Kb + ((size_t)b * 4096 + kk0) * 512;
  f32x4 acc[4][4] = {};
  for (int a0 = 0; a0 < 512; a0 += 32) {
    __syncthreads();
#pragma unroll
    for (int i = 0; i < 2; i++) {
      int j = w + 4 * i;
      int ro = j * 16 + (l >> 2);
      int co = (l & 3) * 8;
      GLOAD16(Ab + (size_t)ro * 512 + a0 + co, &As[j * 512]);
      GLOAD16(Bb + (size_t)ro * 512 + a0 + co, &Bs[j * 512]);
    }
    __syncthreads();
    bf16x8 a[4], bfr[4];
#pragma unroll
    for (int m = 0; m < 4; m++)
      a[m] = *(const bf16x8*)&As[(wr * 64 + m * 16 + lr) * 32 + lg * 8];
#pragma unroll
    for (int n = 0; n < 4; n++)
      bfr[n] = *(const bf16x8*)&Bs[(wc * 64 + n * 16 + lr) * 32 + lg * 8];
#pragma unroll
    for (int m = 0; m < 4; m++)
#pragma unroll
      for (int n = 0; n < 4; n++)
        acc[m][n] = __builtin_amdgcn_mfma_f32_16x16x32_bf16(a[m], bfr[n], acc[m][n], 0, 0, 0);
  }
  float cs[4] = {0.f, 0.f, 0.f, 0.f};
#pragma unroll
  for (int m = 0; m < 4; m++) {
#pragma unroll
    for (int n = 0; n < 4; n++) {
      f32x4 v = acc[m][n];
#pragma unroll
      for (int j = 0; j < 4; j++) {
        float p = __expf(v[j] * SCL);
        cs[n] += p;
        Pst[(wr * 64 + m * 16 + lg * 4 + j) * 136 + wc * 64 + n * 16 + lr] = f2bf(p);
      }
    }
  }
#pragma unroll
  for (int n = 0; n < 4; n++) {
    cs[n] += __shfl_xor(cs[n], 16);
    cs[n] += __shfl_xor(cs[n], 32);
    if (l < 16) red[wr][wc][n][lr] = cs[n];
  }
  __syncthreads();
  if (tid < 128) {
    int wcb = tid >> 6, nn = (tid >> 4) & 3, lrr = tid & 15;
    float v = red[0][wcb][nn][lrr] + red[1][wcb][nn][lrr];
    part[((size_t)(bl * 32 + blockIdx.y)) * 4096 + kk0 + tid] = v;
  }
#pragma unroll
  for (int i = 0; i < 4; i++) {
    int r = i * 32 + (tid >> 3);
#pragma unroll
    for (int j2 = 0; j2 < 2; j2++) {
      int col = (tid & 7) * 8 + j2 * 64;
      *(ushort8_t*)&P[((size_t)bl * 4096 + q0 + r) * 4096 + kk0 + col] =
          *(const ushort8_t*)&Pst[r * 136 + col];
    }
  }
}

// ---------------- K5: linv[bl][k] = 1 / sum_qb part[bl][qb][k] -------------
__global__ __launch_bounds__(256) void k_finl(const float* __restrict__ part,
                                              float* __restrict__ linv) {
  int t = blockIdx.x * 256 + threadIdx.x;   // t < G*4096
  int bl = t >> 12, k = t & 4095;
  float s = 0.f;
#pragma unroll
  for (int qb = 0; qb < 32; qb++)
    s += part[((size_t)(bl * 32 + qb)) * 4096 + k];
  linv[t] = 1.0f / s;
}

// ---------------- K6: Vt[bl][o][k] *= linv[bl][k] -------------------------
__global__ __launch_bounds__(256) void k_scale(u16* __restrict__ Vtg,
                                               const float* __restrict__ linv) {
  size_t i = ((size_t)blockIdx.x * 256 + threadIdx.x) * 8;
  int bl = (int)(i >> 22);
  int k = (int)(i & 4095);
  const float* lp = linv + ((size_t)bl << 12) + k;
  ushort8_t v = *(ushort8_t*)(Vtg + i);
#pragma unroll
  for (int j = 0; j < 8; j++) v[j] = f2bf(bf2f(v[j]) * lp[j]);
  *(ushort8_t*)(Vtg + i) = v;
}

// ---------------- K7: out = P @ Vt'  (256x256 tile, BK=64, dbuf LDS) -------
// 8 waves (2 row-halves x 4 col-quarters), per-wave C = 128x64.
// LDS double-buffered, swizzled (16B chunk ^= row&7).  Staging for tile t+1
// issued at top of tile t body; vmcnt(0) + one raw barrier at bottom.
// Grid: 64*G blocks, XCD-chunked decode: each XCD gets contiguous (b,o) work.
__global__ __launch_bounds__(512, 2) void k_pv(const u16* __restrict__ P,
                                               const u16* __restrict__ Vtg,
                                               float* __restrict__ outg,
                                               int nwg) {
  __shared__ u16 As[2][256 * 64];   // 64KB  (q rows x k)
  __shared__ u16 Bs[2][256 * 64];   // 64KB  (o rows x k)
  const int tid = threadIdx.x;
  const int w = tid >> 6, l = tid & 63;
  const int lr = l & 15, lg = l >> 4;
  const int wr = w >> 2, wc = w & 3;
  // bijective XCD-chunk remap (nwg % 8 == 0)
  const int cpx = nwg >> 3;
  const int swz = (blockIdx.x & 7) * cpx + (blockIdx.x >> 3);
  const int qi = swz & 15, oi = (swz >> 4) & 3, bl = swz >> 6;
  const int q0 = qi * 256, o0 = oi * 256;

  const u16* Abase = P + ((size_t)bl * 4096 + q0) * 4096;
  const u16* Bbase = Vtg + ((size_t)bl * 1024 + o0) * 4096;

  // per-lane staging source offsets (pre-swizzled chunk): issue i covers rows
  // i*64 + w*8 + (l>>3); lane chunk p = l&7 holds global chunk p^(row&7).
  int srow[4], scol[4];
#pragma unroll
  for (int i = 0; i < 4; i++) {
    int r = i * 64 + w * 8 + (l >> 3);
    srow[i] = r;
    scol[i] = ((l & 7) ^ (r & 7)) * 8;
  }

  auto stage = [&](int t, int d) {
    const size_t kofs = (size_t)t * 64;
#pragma unroll
    for (int i = 0; i < 4; i++)
      GLOAD16(Abase + (size_t)srow[i] * 4096 + kofs + scol[i],
              &As[d][i * 4096 + w * 512]);
#pragma unroll
    for (int i = 0; i < 4; i++)
      GLOAD16(Bbase + (size_t)srow[i] * 4096 + kofs + scol[i],
              &Bs[d][i * 4096 + w * 512]);
  };

  f32x4 acc[8][4] = {};

  stage(0, 0);
  asm volatile("s_waitcnt vmcnt(0)" ::: "memory");
  __builtin_amdgcn_s_barrier();
  __builtin_amdgcn_sched_barrier(0);

  const int NT = 64;                     // 4096 / 64
  for (int t = 0; t < NT; t++) {
    const int d = t & 1;
    if (t + 1 < NT) stage(t + 1, d ^ 1);
    // B fragments: rows wc*64 + n*16 + lr, k-sub kk (chunk = kk*4+lg)
    bf16x8 bfr[4][2];
#pragma unroll
    for (int n = 0; n < 4; n++) {
#pragma unroll
      for (int kk = 0; kk < 2; kk++) {
        int r = wc * 64 + n * 16 + lr;
        int c = (kk * 4 + lg) ^ (r & 7);
        bfr[n][kk] = *(const bf16x8*)&Bs[d][r * 64 + c * 8];
      }
    }
#pragma unroll
    for (int m = 0; m < 8; m++) {
      bf16x8 a2[2];
#pragma unroll
      for (int kk = 0; kk < 2; kk++) {
        int r = wr * 128 + m * 16 + lr;
        int c = (kk * 4 + lg) ^ (r & 7);
        a2[kk] = *(const bf16x8*)&As[d][r * 64 + c * 8];
      }
#pragma unroll
      for (int n = 0; n < 4; n++) {
#pragma unroll
        for (int kk = 0; kk < 2; kk++)
          acc[m][n] = __builtin_amdgcn_mfma_f32_16x16x32_bf16(a2[kk], bfr[n][kk],
                                                              acc[m][n], 0, 0, 0);
      }
    }
    asm volatile("s_waitcnt vmcnt(0)" ::: "memory");
    __builtin_amdgcn_s_barrier();
    __builtin_amdgcn_sched_barrier(0);
  }

#pragma unroll
  for (int m = 0; m < 8; m++) {
    int q = q0 + wr * 128 + m * 16 + lg * 4;
#pragma unroll
    for (int n = 0; n < 4; n++) {
      int o = o0 + wc * 64 + n * 16 + lr;
      f32x4 v = acc[m][n];
#pragma unroll
      for (int j = 0; j < 4; j++)
        outg[((size_t)bl * 4096 + q + j) * 1024 + o] = v[j];
    }
  }
}

// ---------------------------------------------------------------------------
extern "C" void kernel_launch(void* const* d_in, const int* in_sizes, int n_in,
                              void* d_out, int out_size, void* d_ws, size_t ws_size,
                              hipStream_t stream) {
  const float* X = (const float*)d_in[0];   // 4*4096*1024
  const float* W = (const float*)d_in[1];   // 1024*2048
  float* out = (float*)d_out;               // 4*4096*1024 fp32
  char* ws = (char*)d_ws;

  int G;
  if (ws_size >= 203489280ull)      G = 4;
  else if (ws_size >= 135299072ull) G = 2;
  else if (ws_size >= 104857600ull) G = 1;
  else return;
  const size_t PB = (size_t)G * 33554432ull;

  u16* Qb  = (u16*)(ws);
  u16* Kb  = (u16*)(ws + 16777216);
  u16* Vt  = (u16*)(ws + 33554432);
  u16* P   = (u16*)(ws + 67108864);
  u16* Xb  = (u16*)(ws + 67108864);
  u16* Wbt = (u16*)(ws + 100663296);
  float* part = (float*)(ws + 67108864 + PB);
  float* linv = (float*)(ws + 67108864 + PB + (size_t)G * 524288ull);

  k_cvt_x<<<dim3(8192), dim3(256), 0, stream>>>(X, Xb);
  k_cvt_w<<<dim3(32, 16), dim3(256), 0, stream>>>(W, Wbt);
  k_qkv<<<dim3(16, 128), dim3(256), 0, stream>>>(Xb, Wbt, Qb, Kb, Vt);
  for (int b0 = 0; b0 < 4; b0 += G) {
    k_sp<<<dim3(32, 32, G), dim3(256), 0, stream>>>(Qb, Kb, P, part, b0);
    k_finl<<<dim3(G * 16), dim3(256), 0, stream>>>(part, linv);
    k_scale<<<dim3(G * 2048), dim3(256), 0, stream>>>(Vt + (size_t)b0 * 4194304, linv);
    int nwg = 64 * G;
    k_pv<<<dim3(nwg), dim3(512), 0, stream>>>(P, Vt + (size_t)b0 * 4194304,
                                              out + (size_t)b0 * 4194304, nwg);
  }
}

// Round 4
// 347.651 us; speedup vs baseline: 3.1126x; 1.0284x over previous
//
#include <hip/hip_runtime.h>
#include <hip/hip_bf16.h>

// ---------------------------------------------------------------------------
// SelfAttention: QKV = X@W ; S = Q K^T / sqrt(512) ; P = softmax(S, axis=q) ;
// out = P @ V.   B=4, S=4096, D_IN=1024, A=512, O=1024.
// Softmax over the *q* axis (per key column).  Strategy: materialize
// P = exp(S) (unnormalized, bf16); fold 1/l into Vt; out = P @ Vt'.
// All three GEMMs share a 256x256-tile, BK=32, 4-deep-ring, counted-vmcnt
// skeleton (T1 XCD swizzle + T2 LDS swizzle + T3/T4 counted pipeline + T5).
// ---------------------------------------------------------------------------

typedef unsigned int u32;
typedef unsigned short u16;
typedef __bf16 bf16x8 __attribute__((ext_vector_type(8)));
typedef float f32x4 __attribute__((ext_vector_type(4)));
typedef u16 ushort8_t __attribute__((ext_vector_type(8)));

#define SCL 0.04419417382415922f   // 1/sqrt(512)

#define GLOAD16(gp, lp)                                                        \
  __builtin_amdgcn_global_load_lds(                                            \
      (const __attribute__((address_space(1))) u32*)(gp),                      \
      (__attribute__((address_space(3))) u32*)(lp), 16, 0, 0)

__device__ __forceinline__ u16 f2bf(float f) {
  union { float f; u32 u; } v; v.f = f;
  u32 r = (v.u + 0x7fffu + ((v.u >> 16) & 1u)) >> 16;   // RNE
  return (u16)r;
}
__device__ __forceinline__ float bf2f(u16 h) {
  union { u32 u; float f; } v; v.u = ((u32)h) << 16;
  return v.f;
}

// ---------------- K1: X fp32 -> bf16 -------------------------------------
__global__ __launch_bounds__(256) void k_cvt_x(const float* __restrict__ X,
                                               u16* __restrict__ Xb) {
  size_t i = ((size_t)blockIdx.x * 256 + threadIdx.x) * 8;
  const float4* p = (const float4*)(X + i);
  float4 a = p[0], b = p[1];
  ushort8_t o;
  o[0] = f2bf(a.x); o[1] = f2bf(a.y); o[2] = f2bf(a.z); o[3] = f2bf(a.w);
  o[4] = f2bf(b.x); o[5] = f2bf(b.y); o[6] = f2bf(b.z); o[7] = f2bf(b.w);
  *(ushort8_t*)(Xb + i) = o;
}

// ---------------- K2: W [1024][2048] fp32 -> Wbt [2048][1024] bf16 --------
__global__ __launch_bounds__(256) void k_cvt_w(const float* __restrict__ W,
                                               u16* __restrict__ Wbt) {
  __shared__ float t[64][65];
  const int e0 = blockIdx.x * 64, d0 = blockIdx.y * 64;
  const int c = threadIdx.x & 63, r4 = threadIdx.x >> 6;
#pragma unroll
  for (int i = 0; i < 16; i++) {
    int d = r4 + i * 4;
    t[d][c] = W[(size_t)(d0 + d) * 2048 + e0 + c];
  }
  __syncthreads();
#pragma unroll
  for (int i = 0; i < 16; i++) {
    int e = r4 + i * 4;
    Wbt[(size_t)(e0 + e) * 1024 + d0 + c] = f2bf(t[c][e]);
  }
}

// ---------------------------------------------------------------------------
// Shared ring-GEMM body: C(256x256) = A(256xK) * B(256xK)^T, BK=32,
// 4-slot LDS ring (slot = A 8192 elems + B 8192 elems), counted vmcnt.
// 8 waves (2 wr x 4 wc), per-wave C = 128x64, acc[8][4] f32x4.
// LDS chunk swizzle: stored chunk q of row r holds global chunk
// q ^ (r&3) ^ ((r>>2)&3)  (free 2-way on ds_read_b128 fragments).
// ---------------------------------------------------------------------------
__device__ __forceinline__ void ring_gemm(const u16* __restrict__ Abase,
                                          const u16* __restrict__ Bbase,
                                          int lda, int ldb, int nt,
                                          u16* lds, f32x4 (&acc)[8][4]) {
  const int tid = threadIdx.x;
  const int w = tid >> 6, l = tid & 63;
  const int lr = l & 15, lg = l >> 4;
  const int wr = w >> 2, wc = w & 3;

  // staging source (per-thread): row r, pre-swizzled global chunk
  const int sr = tid >> 2;                       // 0..127
  const int sc0 = tid & 3;
  // frag LDS byte offsets (slot-relative), swizzled
  int offA[8], offB[4];
#pragma unroll
  for (int m = 0; m < 8; m++) {
    int r = wr * 128 + m * 16 + lr;
    int c = lg ^ (r & 3) ^ ((r >> 2) & 3);
    offA[m] = (r * 32 + c * 8) * 2;
  }
#pragma unroll
  for (int n = 0; n < 4; n++) {
    int r = wc * 64 + n * 16 + lr;
    int c = lg ^ (r & 3) ^ ((r >> 2) & 3);
    offB[n] = 16384 + (r * 32 + c * 8) * 2;
  }

  auto stage = [&](int t) {
    const int s = t & 3;
    const size_t kofs = (size_t)t * 32;
#pragma unroll
    for (int i = 0; i < 2; i++) {
      int r = i * 128 + sr;
      int c = sc0 ^ (r & 3) ^ ((r >> 2) & 3);
      GLOAD16(Abase + (size_t)r * lda + kofs + c * 8,
              lds + s * 16384 + i * 4096 + w * 512);
      GLOAD16(Bbase + (size_t)r * ldb + kofs + c * 8,
              lds + s * 16384 + 8192 + i * 4096 + w * 512);
    }
  };

  stage(0); stage(1); stage(2);
  for (int t = 0; t < nt; t++) {
    if (t + 2 < nt)      asm volatile("s_waitcnt vmcnt(8)" ::: "memory");
    else if (t + 1 < nt) asm volatile("s_waitcnt vmcnt(4)" ::: "memory");
    else                 asm volatile("s_waitcnt vmcnt(0)" ::: "memory");
    __builtin_amdgcn_s_barrier();
    __builtin_amdgcn_sched_barrier(0);
    if (t + 3 < nt) stage(t + 3);
    const char* base = (const char*)lds + (size_t)(t & 3) * 32768;
    bf16x8 a[8], b[4];
#pragma unroll
    for (int n = 0; n < 4; n++) b[n] = *(const bf16x8*)(base + offB[n]);
#pragma unroll
    for (int m = 0; m < 8; m++) a[m] = *(const bf16x8*)(base + offA[m]);
    __builtin_amdgcn_s_setprio(1);
#pragma unroll
    for (int m = 0; m < 8; m++)
#pragma unroll
      for (int n = 0; n < 4; n++)
        acc[m][n] = __builtin_amdgcn_mfma_f32_16x16x32_bf16(a[m], b[n], acc[m][n], 0, 0, 0);
    __builtin_amdgcn_s_setprio(0);
  }
}

// ---------------- K3: QKV GEMM (ring, 256x256) -----------------------------
// C[r][e] = sum_d Xb[r][d]*Wbt[e][d].  e<512 -> Qb ; <1024 -> Kb ; else Vt^T.
__global__ __launch_bounds__(512, 2) void k_qkv(const u16* __restrict__ Xb,
                                                const u16* __restrict__ Wbt,
                                                u16* __restrict__ Qb,
                                                u16* __restrict__ Kb,
                                                u16* __restrict__ Vt) {
  __shared__ u16 lds[65536];
  const int nwg = 512;
  const int cpx = nwg >> 3;
  const int swz = ((int)blockIdx.x & 7) * cpx + ((int)blockIdx.x >> 3);
  const int ci = swz & 7, ri = swz >> 3;
  const int r0 = ri * 256, c0 = ci * 256;

  f32x4 acc[8][4] = {};
  ring_gemm(Xb + (size_t)r0 * 1024, Wbt + (size_t)c0 * 1024, 1024, 1024, 32,
            lds, acc);

  const int tid = threadIdx.x;
  const int w = tid >> 6, l = tid & 63;
  const int lr = l & 15, lg = l >> 4;
  const int wr = w >> 2, wc = w & 3;
  const int bb = r0 >> 12;
  const int s0 = (r0 & 4095) + wr * 128;
#pragma unroll
  for (int m = 0; m < 8; m++) {
    int sb = s0 + m * 16 + lg * 4;
#pragma unroll
    for (int n = 0; n < 4; n++) {
      int e16 = c0 + wc * 64 + n * 16;   // wave-uniform region select
      f32x4 v = acc[m][n];
      if (e16 < 1024) {
        u16* base; int ee;
        if (e16 < 512) { base = Qb; ee = e16 + lr; }
        else           { base = Kb; ee = e16 - 512 + lr; }
#pragma unroll
        for (int j = 0; j < 4; j++)
          base[((size_t)bb * 4096 + sb + j) * 512 + ee] = f2bf(v[j]);
      } else {
        int o = e16 - 1024 + lr;
        u16 pk[4] = { f2bf(v[0]), f2bf(v[1]), f2bf(v[2]), f2bf(v[3]) };
        *(uint2*)(Vt + ((size_t)bb * 1024 + o) * 4096 + sb) = *(uint2*)pk;
      }
    }
  }
}

// ---------------- K4: S-GEMM + exp -> P, column partial sums (ring) --------
// part[bl][qi][k] = sum over this block's 256 q rows of exp(S).
__global__ __launch_bounds__(512, 2) void k_sp(const u16* __restrict__ Qb,
                                               const u16* __restrict__ Kb,
                                               u16* __restrict__ P,
                                               float* __restrict__ part,
                                               int b0, int nwg) {
  __shared__ u16 lds[65536];
  __shared__ float red[2][4][4][16];
  const int cpx = nwg >> 3;
  const int swz = ((int)blockIdx.x & 7) * cpx + ((int)blockIdx.x >> 3);
  const int qi = swz & 15, ki = (swz >> 4) & 15, bl = swz >> 8;
  const int b = b0 + bl;
  const int q0 = qi * 256, kk0 = ki * 256;

  f32x4 acc[8][4] = {};
  ring_gemm(Qb + ((size_t)b * 4096 + q0) * 512,
            Kb + ((size_t)b * 4096 + kk0) * 512, 512, 512, 16, lds, acc);

  const int tid = threadIdx.x;
  const int w = tid >> 6, l = tid & 63;
  const int lr = l & 15, lg = l >> 4;
  const int wr = w >> 2, wc = w & 3;

  // exp in place + column sums
  float cs[4] = {0.f, 0.f, 0.f, 0.f};
#pragma unroll
  for (int m = 0; m < 8; m++)
#pragma unroll
    for (int n = 0; n < 4; n++)
#pragma unroll
      for (int j = 0; j < 4; j++) {
        float p = __expf(acc[m][n][j] * SCL);
        acc[m][n][j] = p;
        cs[n] += p;
      }
#pragma unroll
  for (int n = 0; n < 4; n++) {
    cs[n] += __shfl_xor(cs[n], 16);
    cs[n] += __shfl_xor(cs[n], 32);
  }
  if (l < 16)
#pragma unroll
    for (int n = 0; n < 4; n++) red[wr][wc][n][l] = cs[n];
  __syncthreads();
  if (tid < 256) {
    int k = tid;
    float v = red[0][k >> 6][(k >> 4) & 3][k & 15] +
              red[1][k >> 6][(k >> 4) & 3][k & 15];
    part[((size_t)bl * 16 + qi) * 4096 + kk0 + k] = v;
  }

  // P write via LDS transpose (reuse ring LDS; pad 276 -> conflict-free)
  u16* Pst = lds;
  for (int cch = 0; cch < 2; cch++) {
    __syncthreads();
    if (wr == cch) {
#pragma unroll
      for (int m = 0; m < 8; m++)
#pragma unroll
        for (int n = 0; n < 4; n++)
#pragma unroll
          for (int j = 0; j < 4; j++)
            Pst[(m * 16 + lg * 4 + j) * 276 + wc * 64 + n * 16 + lr] =
                f2bf(acc[m][n][j]);
    }
    __syncthreads();
#pragma unroll
    for (int i = 0; i < 8; i++) {
      int rrow = i * 16 + (tid >> 5);
      int col = (tid & 31) * 8;
      *(ushort8_t*)&P[((size_t)bl * 4096 + q0 + cch * 128 + rrow) * 4096 +
                      kk0 + col] = *(const ushort8_t*)&Pst[rrow * 276 + col];
    }
  }
}

// ---------------- K5: linv[bl][k] = 1 / sum_qi part[bl][qi][k] -------------
__global__ __launch_bounds__(256) void k_finl(const float* __restrict__ part,
                                              float* __restrict__ linv) {
  int t = blockIdx.x * 256 + threadIdx.x;   // t < G*4096
  int bl = t >> 12, k = t & 4095;
  float s = 0.f;
#pragma unroll
  for (int qb = 0; qb < 16; qb++)
    s += part[((size_t)(bl * 16 + qb)) * 4096 + k];
  linv[t] = 1.0f / s;
}

// ---------------- K6: Vt[bl][o][k] *= linv[bl][k] -------------------------
__global__ __launch_bounds__(256) void k_scale(u16* __restrict__ Vtg,
                                               const float* __restrict__ linv) {
  size_t i = ((size_t)blockIdx.x * 256 + threadIdx.x) * 8;
  int bl = (int)(i >> 22);
  int k = (int)(i & 4095);
  const float* lp = linv + ((size_t)bl << 12) + k;
  ushort8_t v = *(ushort8_t*)(Vtg + i);
#pragma unroll
  for (int j = 0; j < 8; j++) v[j] = f2bf(bf2f(v[j]) * lp[j]);
  *(ushort8_t*)(Vtg + i) = v;
}

// ---------------- K7: out = P @ Vt'  (ring, 256x256) -----------------------
__global__ __launch_bounds__(512, 2) void k_pv(const u16* __restrict__ P,
                                               const u16* __restrict__ Vtg,
                                               float* __restrict__ outg,
                                               int nwg) {
  __shared__ u16 lds[65536];
  const int cpx = nwg >> 3;
  const int swz = ((int)blockIdx.x & 7) * cpx + ((int)blockIdx.x >> 3);
  const int qi = swz & 15, oi = (swz >> 4) & 3, bl = swz >> 6;
  const int q0 = qi * 256, o0 = oi * 256;

  f32x4 acc[8][4] = {};
  ring_gemm(P + ((size_t)bl * 4096 + q0) * 4096,
            Vtg + ((size_t)bl * 1024 + o0) * 4096, 4096, 4096, 128, lds, acc);

  const int tid = threadIdx.x;
  const int w = tid >> 6, l = tid & 63;
  const int lr = l & 15, lg = l >> 4;
  const int wr = w >> 2, wc = w & 3;
#pragma unroll
  for (int m = 0; m < 8; m++) {
    int q = q0 + wr * 128 + m * 16 + lg * 4;
#pragma unroll
    for (int n = 0; n < 4; n++) {
      int o = o0 + wc * 64 + n * 16 + lr;
      f32x4 v = acc[m][n];
#pragma unroll
      for (int j = 0; j < 4; j++)
        outg[((size_t)bl * 4096 + q + j) * 1024 + o] = v[j];
    }
  }
}

// ---------------------------------------------------------------------------
extern "C" void kernel_launch(void* const* d_in, const int* in_sizes, int n_in,
                              void* d_out, int out_size, void* d_ws, size_t ws_size,
                              hipStream_t stream) {
  const float* X = (const float*)d_in[0];   // 4*4096*1024
  const float* W = (const float*)d_in[1];   // 1024*2048
  float* out = (float*)d_out;               // 4*4096*1024 fp32
  char* ws = (char*)d_ws;

  int G;
  if (ws_size >= 203489280ull)      G = 4;
  else if (ws_size >= 135299072ull) G = 2;
  else if (ws_size >= 104857600ull) G = 1;
  else return;
  const size_t PB = (size_t)G * 33554432ull;

  u16* Qb  = (u16*)(ws);
  u16* Kb  = (u16*)(ws + 16777216);
  u16* Vt  = (u16*)(ws + 33554432);
  u16* P   = (u16*)(ws + 67108864);
  u16* Xb  = (u16*)(ws + 67108864);
  u16* Wbt = (u16*)(ws + 100663296);
  float* part = (float*)(ws + 67108864 + PB);
  float* linv = (float*)(ws + 67108864 + PB + (size_t)G * 262144ull);

  k_cvt_x<<<dim3(8192), dim3(256), 0, stream>>>(X, Xb);
  k_cvt_w<<<dim3(32, 16), dim3(256), 0, stream>>>(W, Wbt);
  k_qkv<<<dim3(512), dim3(512), 0, stream>>>(Xb, Wbt, Qb, Kb, Vt);
  for (int b0 = 0; b0 < 4; b0 += G) {
    int nwg_sp = 256 * G;
    k_sp<<<dim3(nwg_sp), dim3(512), 0, stream>>>(Qb, Kb, P, part, b0, nwg_sp);
    k_finl<<<dim3(G * 16), dim3(256), 0, stream>>>(part, linv);
    k_scale<<<dim3(G * 2048), dim3(256), 0, stream>>>(Vt + (size_t)b0 * 4194304, linv);
    int nwg = 64 * G;
    k_pv<<<dim3(nwg), dim3(512), 0, stream>>>(P, Vt + (size_t)b0 * 4194304,
                                              out + (size_t)b0 * 4194304, nwg);
  }
}

// Round 5
// 322.653 us; speedup vs baseline: 3.3537x; 1.0775x over previous
//
#include <hip/hip_runtime.h>
#include <hip/hip_bf16.h>

// ---------------------------------------------------------------------------
// SelfAttention: QKV = X@W ; S = Q K^T / sqrt(512) ; P = softmax(S, axis=q) ;
// out = P @ V.   B=4, S=4096, D_IN=1024, A=512, O=1024.
// Softmax over the *q* axis (per key column).  Strategy: materialize
// P = exp(S) (unnormalized, bf16); fold 1/l into Vt; out = P @ Vt'.
// All three GEMMs share a 256x256-tile, BK=64, 8-phase counted-vmcnt
// schedule (T1 + T2 conflict-free swizzle + T3/T4 + T5).
// ---------------------------------------------------------------------------

typedef unsigned int u32;
typedef unsigned short u16;
typedef __bf16 bf16x8 __attribute__((ext_vector_type(8)));
typedef float f32x4 __attribute__((ext_vector_type(4)));
typedef u16 ushort8_t __attribute__((ext_vector_type(8)));

#define SCL 0.04419417382415922f   // 1/sqrt(512)

#define GLOAD16(gp, lp)                                                        \
  __builtin_amdgcn_global_load_lds(                                            \
      (const __attribute__((address_space(1))) u32*)(gp),                      \
      (__attribute__((address_space(3))) u32*)(lp), 16, 0, 0)

__device__ __forceinline__ u16 f2bf(float f) {
  union { float f; u32 u; } v; v.f = f;
  u32 r = (v.u + 0x7fffu + ((v.u >> 16) & 1u)) >> 16;   // RNE
  return (u16)r;
}
__device__ __forceinline__ float bf2f(u16 h) {
  union { u32 u; float f; } v; v.u = ((u32)h) << 16;
  return v.f;
}

// ---------------- K1: X fp32 -> bf16 -------------------------------------
__global__ __launch_bounds__(256) void k_cvt_x(const float* __restrict__ X,
                                               u16* __restrict__ Xb) {
  size_t i = ((size_t)blockIdx.x * 256 + threadIdx.x) * 8;
  const float4* p = (const float4*)(X + i);
  float4 a = p[0], b = p[1];
  ushort8_t o;
  o[0] = f2bf(a.x); o[1] = f2bf(a.y); o[2] = f2bf(a.z); o[3] = f2bf(a.w);
  o[4] = f2bf(b.x); o[5] = f2bf(b.y); o[6] = f2bf(b.z); o[7] = f2bf(b.w);
  *(ushort8_t*)(Xb + i) = o;
}

// ---------------- K2: W [1024][2048] fp32 -> Wbt [2048][1024] bf16 --------
__global__ __launch_bounds__(256) void k_cvt_w(const float* __restrict__ W,
                                               u16* __restrict__ Wbt) {
  __shared__ float t[64][65];
  const int e0 = blockIdx.x * 64, d0 = blockIdx.y * 64;
  const int c = threadIdx.x & 63, r4 = threadIdx.x >> 6;
#pragma unroll
  for (int i = 0; i < 16; i++) {
    int d = r4 + i * 4;
    t[d][c] = W[(size_t)(d0 + d) * 2048 + e0 + c];
  }
  __syncthreads();
#pragma unroll
  for (int i = 0; i < 16; i++) {
    int e = r4 + i * 4;
    Wbt[(size_t)(e0 + e) * 1024 + d0 + c] = f2bf(t[c][e]);
  }
}

// ---------------------------------------------------------------------------
// 8-phase GEMM body: C(256x256) = A(256xK) * B(256xK)^T, BK=64.
// LDS 128KB: A slots 0/1 @ 0/32KB (even/odd K-tiles), B slots @ 64/96KB.
// Slot = [256 rows][64 cols] bf16, 16B chunk c of row r holds global chunk
// c ^ (r&7)  (measured conflict-free).  8 waves (2 wr x 4 wc), per-wave
// C = 128x64 = acc[8][4].  Per phase: ds-read quadrant (+B at p1/p5),
// stage one half-tile (2 x global_load_lds), barrier, lgkmcnt(0),
// 16 MFMA (setprio), [vmcnt(6) at p4/p8], barrier.
// Staging order per iter i (kt=2i): p1:A(kt+1)L p2:B(kt+2)h0 p3:B(kt+2)h1
// p4:A(kt+2)E p5:A(kt+2)L p6:B(kt+3)h0 p7:B(kt+3)h1 p8:A(kt+3)E
// where E = row-blocks {0-63,128-191}, L = {64-127,192-255} (read-liveness).
// ---------------------------------------------------------------------------
__device__ __forceinline__ void gemm8(const u16* __restrict__ Ab,
                                      const u16* __restrict__ Bb,
                                      int lda, int ldb, int NT,
                                      u16* lds, f32x4 (&acc)[8][4]) {
  const int tid = threadIdx.x;
  const int w = tid >> 6, l = tid & 63;
  const int lr = l & 15, lg = l >> 4;
  const int wr = w >> 2, wc = w & 3;

  const int gcs = (tid & 7) ^ ((tid >> 3) & 7);
  const u16* pA = Ab + (size_t)(tid >> 3) * lda + gcs * 8;
  const u16* pB = Bb + (size_t)(tid >> 3) * ldb + gcs * 8;

  const int ac0 = (lg ^ (lr & 7)) * 8;
  const int ac1 = ((4 + lg) ^ (lr & 7)) * 8;
  const int aoff = (wr * 128 + lr) * 64;
  const int boff = (wc * 64 + lr) * 64;

  bf16x8 bfrag[4][2];

  auto stA = [&](int kt, int R) {
    GLOAD16(pA + (size_t)R * lda + kt * 64,
            lds + ((kt & 1) << 14) + R * 64 + (w << 9));
  };
  auto stB = [&](int kt, int R) {
    GLOAD16(pB + (size_t)R * ldb + kt * 64,
            lds + 32768 + ((kt & 1) << 14) + R * 64 + (w << 9));
  };

  auto phase = [&](int qd, int asl, bool loadB, int bsl, auto&& stagefn,
                   int ckpt) {
    if (loadB) {
#pragma unroll
      for (int n = 0; n < 4; n++) {
        bfrag[n][0] = *(const bf16x8*)&lds[32768 + (bsl << 14) + boff + n * 1024 + ac0];
        bfrag[n][1] = *(const bf16x8*)&lds[32768 + (bsl << 14) + boff + n * 1024 + ac1];
      }
    }
    bf16x8 a[2][2];
#pragma unroll
    for (int m2 = 0; m2 < 2; m2++) {
      a[m2][0] = *(const bf16x8*)&lds[(asl << 14) + aoff + qd * 2048 + m2 * 1024 + ac0];
      a[m2][1] = *(const bf16x8*)&lds[(asl << 14) + aoff + qd * 2048 + m2 * 1024 + ac1];
    }
    stagefn();
    __builtin_amdgcn_s_barrier();
    asm volatile("s_waitcnt lgkmcnt(0)" ::: "memory");
    __builtin_amdgcn_sched_barrier(0);
    __builtin_amdgcn_s_setprio(1);
#pragma unroll
    for (int m2 = 0; m2 < 2; m2++)
#pragma unroll
      for (int n = 0; n < 4; n++)
#pragma unroll
        for (int kk = 0; kk < 2; kk++)
          acc[qd * 2 + m2][n] = __builtin_amdgcn_mfma_f32_16x16x32_bf16(
              a[m2][kk], bfrag[n][kk], acc[qd * 2 + m2][n], 0, 0, 0);
    __builtin_amdgcn_s_setprio(0);
    if (ckpt == 6) asm volatile("s_waitcnt vmcnt(6)" ::: "memory");
    else if (ckpt == 0) asm volatile("s_waitcnt vmcnt(0)" ::: "memory");
    __builtin_amdgcn_s_barrier();
    __builtin_amdgcn_sched_barrier(0);
  };
  auto nostage = [&] {};

  // prologue: B(0), A(0)E, A(0)L, B(1), A(1)E  (14 issues); drain to 6.
  stB(0, 0); stB(0, 64); stB(0, 128); stB(0, 192);
  stA(0, 0); stA(0, 128);
  stA(0, 64); stA(0, 192);
  stB(1, 0); stB(1, 64); stB(1, 128); stB(1, 192);
  stA(1, 0); stA(1, 128);
  asm volatile("s_waitcnt vmcnt(6)" ::: "memory");
  __builtin_amdgcn_s_barrier();
  __builtin_amdgcn_sched_barrier(0);

  const int NI = NT >> 1;
  for (int i = 0; i < NI - 1; i++) {
    const int kt = 2 * i;
    phase(0, 0, true , 0, [&] { stA(kt + 1, 64); stA(kt + 1, 192); }, -1);
    phase(1, 0, false, 0, [&] { stB(kt + 2, 0);  stB(kt + 2, 64);  }, -1);
    phase(2, 0, false, 0, [&] { stB(kt + 2, 128); stB(kt + 2, 192); }, -1);
    phase(3, 0, false, 0, [&] { stA(kt + 2, 0);  stA(kt + 2, 128); }, 6);
    phase(0, 1, true , 1, [&] { stA(kt + 2, 64); stA(kt + 2, 192); }, -1);
    phase(1, 1, false, 1, [&] { stB(kt + 3, 0);  stB(kt + 3, 64);  }, -1);
    phase(2, 1, false, 1, [&] { stB(kt + 3, 128); stB(kt + 3, 192); }, -1);
    phase(3, 1, false, 1, [&] { stA(kt + 3, 0);  stA(kt + 3, 128); }, 6);
  }
  {
    const int kt = 2 * (NI - 1);
    phase(0, 0, true , 0, [&] { stA(kt + 1, 64); stA(kt + 1, 192); }, -1);
    phase(1, 0, false, 0, nostage, -1);
    phase(2, 0, false, 0, nostage, -1);
    phase(3, 0, false, 0, nostage, 0);
    phase(0, 1, true , 1, nostage, -1);
    phase(1, 1, false, 1, nostage, -1);
    phase(2, 1, false, 1, nostage, -1);
    phase(3, 1, false, 1, nostage, -1);
  }
}

// ---------------- K3: QKV GEMM (8-phase, 256x256) --------------------------
// C[r][e] = sum_d Xb[r][d]*Wbt[e][d].  e<512 -> Qb ; <1024 -> Kb ; else Vt^T.
__global__ __launch_bounds__(512, 2) void k_qkv(const u16* __restrict__ Xb,
                                                const u16* __restrict__ Wbt,
                                                u16* __restrict__ Qb,
                                                u16* __restrict__ Kb,
                                                u16* __restrict__ Vt) {
  __shared__ u16 lds[65536];
  const int nwg = 512;
  const int cpx = nwg >> 3;
  const int swz = ((int)blockIdx.x & 7) * cpx + ((int)blockIdx.x >> 3);
  const int ci = swz & 7, ri = swz >> 3;
  const int r0 = ri * 256, c0 = ci * 256;

  f32x4 acc[8][4] = {};
  gemm8(Xb + (size_t)r0 * 1024, Wbt + (size_t)c0 * 1024, 1024, 1024, 16,
        lds, acc);

  const int tid = threadIdx.x;
  const int w = tid >> 6, l = tid & 63;
  const int lr = l & 15, lg = l >> 4;
  const int wr = w >> 2, wc = w & 3;
  const int bb = r0 >> 12;
  const int s0 = (r0 & 4095) + wr * 128;
#pragma unroll
  for (int m = 0; m < 8; m++) {
    int sb = s0 + m * 16 + lg * 4;
#pragma unroll
    for (int n = 0; n < 4; n++) {
      int e16 = c0 + wc * 64 + n * 16;   // wave-uniform region select
      f32x4 v = acc[m][n];
      if (e16 < 1024) {
        u16* base; int ee;
        if (e16 < 512) { base = Qb; ee = e16 + lr; }
        else           { base = Kb; ee = e16 - 512 + lr; }
#pragma unroll
        for (int j = 0; j < 4; j++)
          base[((size_t)bb * 4096 + sb + j) * 512 + ee] = f2bf(v[j]);
      } else {
        int o = e16 - 1024 + lr;
        u16 pk[4] = { f2bf(v[0]), f2bf(v[1]), f2bf(v[2]), f2bf(v[3]) };
        *(uint2*)(Vt + ((size_t)bb * 1024 + o) * 4096 + sb) = *(uint2*)pk;
      }
    }
  }
}

// ---------------- K4: S-GEMM + exp -> P, column partial sums ---------------
__global__ __launch_bounds__(512, 2) void k_sp(const u16* __restrict__ Qb,
                                               const u16* __restrict__ Kb,
                                               u16* __restrict__ P,
                                               float* __restrict__ part,
                                               int b0, int nwg) {
  __shared__ u16 lds[65536];
  __shared__ float red[2][4][4][16];
  const int cpx = nwg >> 3;
  const int swz = ((int)blockIdx.x & 7) * cpx + ((int)blockIdx.x >> 3);
  const int qi = swz & 15, ki = (swz >> 4) & 15, bl = swz >> 8;
  const int b = b0 + bl;
  const int q0 = qi * 256, kk0 = ki * 256;

  f32x4 acc[8][4] = {};
  gemm8(Qb + ((size_t)b * 4096 + q0) * 512,
        Kb + ((size_t)b * 4096 + kk0) * 512, 512, 512, 8, lds, acc);

  const int tid = threadIdx.x;
  const int w = tid >> 6, l = tid & 63;
  const int lr = l & 15, lg = l >> 4;
  const int wr = w >> 2, wc = w & 3;

  // exp in place + column sums
  float cs[4] = {0.f, 0.f, 0.f, 0.f};
#pragma unroll
  for (int m = 0; m < 8; m++)
#pragma unroll
    for (int n = 0; n < 4; n++)
#pragma unroll
      for (int j = 0; j < 4; j++) {
        float p = __expf(acc[m][n][j] * SCL);
        acc[m][n][j] = p;
        cs[n] += p;
      }
#pragma unroll
  for (int n = 0; n < 4; n++) {
    cs[n] += __shfl_xor(cs[n], 16);
    cs[n] += __shfl_xor(cs[n], 32);
  }
  if (l < 16)
#pragma unroll
    for (int n = 0; n < 4; n++) red[wr][wc][n][l] = cs[n];
  __syncthreads();
  if (tid < 256) {
    int k = tid;
    float v = red[0][k >> 6][(k >> 4) & 3][k & 15] +
              red[1][k >> 6][(k >> 4) & 3][k & 15];
    part[((size_t)bl * 16 + qi) * 4096 + kk0 + k] = v;
  }

  // P write via LDS transpose (reuse gemm LDS; pad 276 -> conflict-free)
  u16* Pst = lds;
  for (int cch = 0; cch < 2; cch++) {
    __syncthreads();
    if (wr == cch) {
#pragma unroll
      for (int m = 0; m < 8; m++)
#pragma unroll
        for (int n = 0; n < 4; n++)
#pragma unroll
          for (int j = 0; j < 4; j++)
            Pst[(m * 16 + lg * 4 + j) * 276 + wc * 64 + n * 16 + lr] =
                f2bf(acc[m][n][j]);
    }
    __syncthreads();
#pragma unroll
    for (int i = 0; i < 8; i++) {
      int rrow = i * 16 + (tid >> 5);
      int col = (tid & 31) * 8;
      *(ushort8_t*)&P[((size_t)bl * 4096 + q0 + cch * 128 + rrow) * 4096 +
                      kk0 + col] = *(const ushort8_t*)&Pst[rrow * 276 + col];
    }
  }
}

// ---------------- K5: linv[bl][k] = 1 / sum_qi part[bl][qi][k] -------------
__global__ __launch_bounds__(256) void k_finl(const float* __restrict__ part,
                                              float* __restrict__ linv) {
  int t = blockIdx.x * 256 + threadIdx.x;   // t < G*4096
  int bl = t >> 12, k = t & 4095;
  float s = 0.f;
#pragma unroll
  for (int qb = 0; qb < 16; qb++)
    s += part[((size_t)(bl * 16 + qb)) * 4096 + k];
  linv[t] = 1.0f / s;
}

// ---------------- K6: Vt[bl][o][k] *= linv[bl][k] -------------------------
__global__ __launch_bounds__(256) void k_scale(u16* __restrict__ Vtg,
                                               const float* __restrict__ linv) {
  size_t i = ((size_t)blockIdx.x * 256 + threadIdx.x) * 8;
  int bl = (int)(i >> 22);
  int k = (int)(i & 4095);
  const float* lp = linv + ((size_t)bl << 12) + k;
  ushort8_t v = *(ushort8_t*)(Vtg + i);
#pragma unroll
  for (int j = 0; j < 8; j++) v[j] = f2bf(bf2f(v[j]) * lp[j]);
  *(ushort8_t*)(Vtg + i) = v;
}

// ---------------- K7: out = P @ Vt'  (8-phase, 256x256) --------------------
__global__ __launch_bounds__(512, 2) void k_pv(const u16* __restrict__ P,
                                               const u16* __restrict__ Vtg,
                                               float* __restrict__ outg,
                                               int nwg) {
  __shared__ u16 lds[65536];
  const int cpx = nwg >> 3;
  const int swz = ((int)blockIdx.x & 7) * cpx + ((int)blockIdx.x >> 3);
  const int qi = swz & 15, oi = (swz >> 4) & 3, bl = swz >> 6;
  const int q0 = qi * 256, o0 = oi * 256;

  f32x4 acc[8][4] = {};
  gemm8(P + ((size_t)bl * 4096 + q0) * 4096,
        Vtg + ((size_t)bl * 1024 + o0) * 4096, 4096, 4096, 64, lds, acc);

  const int tid = threadIdx.x;
  const int w = tid >> 6, l = tid & 63;
  const int lr = l & 15, lg = l >> 4;
  const int wr = w >> 2, wc = w & 3;
#pragma unroll
  for (int m = 0; m < 8; m++) {
    int q = q0 + wr * 128 + m * 16 + lg * 4;
#pragma unroll
    for (int n = 0; n < 4; n++) {
      int o = o0 + wc * 64 + n * 16 + lr;
      f32x4 v = acc[m][n];
#pragma unroll
      for (int j = 0; j < 4; j++)
        outg[((size_t)bl * 4096 + q + j) * 1024 + o] = v[j];
    }
  }
}

// ---------------------------------------------------------------------------
extern "C" void kernel_launch(void* const* d_in, const int* in_sizes, int n_in,
                              void* d_out, int out_size, void* d_ws, size_t ws_size,
                              hipStream_t stream) {
  const float* X = (const float*)d_in[0];   // 4*4096*1024
  const float* W = (const float*)d_in[1];   // 1024*2048
  float* out = (float*)d_out;               // 4*4096*1024 fp32
  char* ws = (char*)d_ws;

  int G;
  if (ws_size >= 203489280ull)      G = 4;
  else if (ws_size >= 135299072ull) G = 2;
  else if (ws_size >= 104857600ull) G = 1;
  else return;
  const size_t PB = (size_t)G * 33554432ull;

  u16* Qb  = (u16*)(ws);
  u16* Kb  = (u16*)(ws + 16777216);
  u16* Vt  = (u16*)(ws + 33554432);
  u16* P   = (u16*)(ws + 67108864);
  u16* Xb  = (u16*)(ws + 67108864);
  u16* Wbt = (u16*)(ws + 100663296);
  float* part = (float*)(ws + 67108864 + PB);
  float* linv = (float*)(ws + 67108864 + PB + (size_t)G * 262144ull);

  k_cvt_x<<<dim3(8192), dim3(256), 0, stream>>>(X, Xb);
  k_cvt_w<<<dim3(32, 16), dim3(256), 0, stream>>>(W, Wbt);
  k_qkv<<<dim3(512), dim3(512), 0, stream>>>(Xb, Wbt, Qb, Kb, Vt);
  for (int b0 = 0; b0 < 4; b0 += G) {
    int nwg_sp = 256 * G;
    k_sp<<<dim3(nwg_sp), dim3(512), 0, stream>>>(Qb, Kb, P, part, b0, nwg_sp);
    k_finl<<<dim3(G * 16), dim3(256), 0, stream>>>(part, linv);
    k_scale<<<dim3(G * 2048), dim3(256), 0, stream>>>(Vt + (size_t)b0 * 4194304, linv);
    int nwg = 64 * G;
    k_pv<<<dim3(nwg), dim3(512), 0, stream>>>(P, Vt + (size_t)b0 * 4194304,
                                              out + (size_t)b0 * 4194304, nwg);
  }
}